// Round 2
// baseline (293.645 us; speedup 1.0000x reference)
//
#include <hip/hip_runtime.h>

// QuantileLoss: scalar = ( sum_rows[ (p0-t0)^2+(p1-t1)^2+(p2-t2)^2 + 2*lower ] ) / (5N)
// lower = p3>p2 ? 1000 : (p3 > 0.95*t2 ? 0 : (p3-0.95*t2)^2)
//
// R1 (row loads, no LDS):   101 us, eff 2.66 TB/s read
// R2 (LDS staged):          105 us
// R3 (NT 160B chunks):      150 us, 392 MB fetched, eff 2.61 TB/s
// R4 (NT + pipeline):       ~95 us partial
// R5 (LDS, no atomics):     99.8 us, FETCH 134 MB (50% L3 hit), HBM 1.35 TB/s,
//                           VALU 6%, occ 25%, eff 2.69 TB/s
// Invariant: every structure consumes reads at ~2.7 TB/s whether served by HBM
// or L3; the harness's own fill writes at 6.7 TB/s. Either (a) all variants were
// parallelism-starved (barrier lockstep, 2 blocks/CU, shallow in-flight), or
// (b) the XCD read path caps at ~2.7 TB/s.
// R6 (this): the discriminating experiment for (a): register-only, BARRIER-FREE,
// full-occupancy. 4 consecutive rows/thread = 5x dwordx4 (preds) + 3x dwordx4
// (target), all 8 loads independent and in flight (128 B/thread; no LDS ->
// 8 waves/SIMD -> ~262 KB/CU in flight, 4x R5), compute straight from registers,
// one syncthreads at the 32 B cross-wave reduce. If this also lands ~100 us,
// (b) is established and we are at the structural roofline.

#define NROWS 8388608                       // 2^23
#define RPT 4                               // rows per thread
#define THREADS 256
#define GRID (NROWS / (RPT * THREADS))      // 8192 blocks

typedef float v4f __attribute__((ext_vector_type(4)));

__global__ void __launch_bounds__(256) qloss_partial(
    const float* __restrict__ preds,
    const float* __restrict__ target,
    double* __restrict__ ws)
{
    const int t = threadIdx.x;
    const size_t g = (size_t)blockIdx.x * THREADS + t;  // row-group id (4 rows)

    // 4 consecutive rows: preds floats [20g, 20g+20) = 5 aligned v4f,
    //                     target floats [12g, 12g+12) = 3 aligned v4f.
    const v4f* gp = (const v4f*)preds  + 5 * g;
    const v4f* gt = (const v4f*)target + 3 * g;

    v4f P[5], T[3];
    #pragma unroll
    for (int k = 0; k < 5; ++k) P[k] = gp[k];           // independent, all in flight
    #pragma unroll
    for (int k = 0; k < 3; ++k) T[k] = gt[k];

    float sum = 0.0f;
    #pragma unroll
    for (int r = 0; r < RPT; ++r) {
        const float p0 = P[(5*r+0) >> 2][(5*r+0) & 3];
        const float p1 = P[(5*r+1) >> 2][(5*r+1) & 3];
        const float p2 = P[(5*r+2) >> 2][(5*r+2) & 3];
        const float p3 = P[(5*r+3) >> 2][(5*r+3) & 3];
        const float t0 = T[(3*r+0) >> 2][(3*r+0) & 3];
        const float t1 = T[(3*r+1) >> 2][(3*r+1) & 3];
        const float t2 = T[(3*r+2) >> 2][(3*r+2) & 3];

        const float a0 = p0 - t0;
        const float a1 = p1 - t1;
        const float a2 = p2 - t2;
        const float m  = a0*a0 + a1*a1 + a2*a2;

        const float q = t2 * 0.95f;
        const float d = p3 - q;
        const float lower = (p3 > p2) ? 1000.0f : ((p3 > q) ? 0.0f : d * d);

        sum += m + 2.0f * lower;
    }
    double acc = (double)sum;

    // wave64 shuffle reduce -> per-block partial. No atomics.
    #pragma unroll
    for (int off = 32; off > 0; off >>= 1)
        acc += __shfl_down(acc, off, 64);

    __shared__ double red[4];
    const int lane = t & 63;
    const int wave = t >> 6;
    if (lane == 0) red[wave] = acc;
    __syncthreads();

    if (t == 0)
        ws[blockIdx.x] = red[0] + red[1] + red[2] + red[3];
}

__global__ void __launch_bounds__(256) qloss_final(
    const double* __restrict__ ws, float* __restrict__ out)
{
    const int t = threadIdx.x;
    double acc = 0.0;
    #pragma unroll
    for (int i = 0; i < GRID / 256; ++i)    // 32 partials/thread, 64 KB total
        acc += ws[t + i * 256];

    #pragma unroll
    for (int off = 32; off > 0; off >>= 1)
        acc += __shfl_down(acc, off, 64);

    __shared__ double red[4];
    const int lane = t & 63;
    const int wave = t >> 6;
    if (lane == 0) red[wave] = acc;
    __syncthreads();

    if (t == 0)
        *out = (float)((red[0] + red[1] + red[2] + red[3]) / (5.0 * (double)NROWS));
}

extern "C" void kernel_launch(void* const* d_in, const int* in_sizes, int n_in,
                              void* d_out, int out_size, void* d_ws, size_t ws_size,
                              hipStream_t stream)
{
    const float* preds  = (const float*)d_in[0];
    const float* target = (const float*)d_in[1];
    float* out  = (float*)d_out;
    double* ws  = (double*)d_ws;

    // Every ws slot [0, GRID) is overwritten by qloss_partial before qloss_final
    // reads it -> no memset needed despite workspace poisoning.
    qloss_partial<<<GRID, THREADS, 0, stream>>>(preds, target, ws);
    qloss_final<<<1, 256, 0, stream>>>(ws, out);
}